// Round 1
// 581.441 us; speedup vs baseline: 1.3516x; 1.3516x over previous
//
#include <hip/hip_runtime.h>
#include <math.h>

// Clusterator soft k-means: N=200000, D=256, K=64, 11 iterations.
// v3: eliminate global X^T entirely — derive xt_lds from x_lds via in-register
//     8x8 f16 transpose (v_perm_b32). sync1 becomes lgkm-only barrier (no vmcnt
//     drain: xt no longer comes from global_load_lds). Parallel 2-stage reduce.
//     Coalesced float4 r_out stores.
// v1 fallback (round-1 fp32 kernel) if ws_size too small for f16 copies.

#define N_ROWS 200000
#define DIM 256
#define KC 64
#define NUM_ITER 11
#define TR 64
#define NTILES (N_ROWS / TR)  // 3125
#define EPSV 1e-8f
#define NB 256
#define NG2 8  // reduce stage-1 groups (32 partials each)

typedef _Float16 half8 __attribute__((ext_vector_type(8)));
typedef _Float16 half4 __attribute__((ext_vector_type(4)));
typedef float f32x4 __attribute__((ext_vector_type(4)));

typedef __attribute__((address_space(3))) void as3_void;
typedef __attribute__((address_space(1))) void as1_void;

__device__ __forceinline__ void glds16(const void* g, void* l) {
  __builtin_amdgcn_global_load_lds((const as1_void*)g, (as3_void*)l, 16, 0, 0);
}

__device__ __forceinline__ float wave_reduce_sum(float v) {
#pragma unroll
  for (int off = 32; off > 0; off >>= 1) v += __shfl_xor(v, off, 64);
  return v;
}

// LDS-only barrier: orders ds_write -> barrier -> ds_read across waves without
// draining vmcnt (global_load_lds prefetches stay in flight across it).
__device__ __forceinline__ void barrier_lgkm_only() {
  __builtin_amdgcn_sched_barrier(0);
  asm volatile("s_waitcnt lgkmcnt(0)" ::: "memory");
  __builtin_amdgcn_s_barrier();
  __builtin_amdgcn_sched_barrier(0);
}

// ---------------- prep kernels ----------------

// inv_norm + f16 row-major copy of embeds
__global__ void rn_convert_kernel(const float* __restrict__ embeds,
                                  float* __restrict__ inv_norm,
                                  _Float16* __restrict__ Xh) {
  int gw = (blockIdx.x * blockDim.x + threadIdx.x) >> 6;
  int lane = threadIdx.x & 63;
  int nw = (gridDim.x * blockDim.x) >> 6;
  for (int row = gw; row < N_ROWS; row += nw) {
    float4 v = *(const float4*)(embeds + (size_t)row * DIM + 4 * lane);
    float s = v.x * v.x;
    s = fmaf(v.y, v.y, s); s = fmaf(v.z, v.z, s); s = fmaf(v.w, v.w, s);
    s = wave_reduce_sum(s);
    if (lane == 0) inv_norm[row] = 1.0f / fmaxf(sqrtf(s), EPSV);
    half4 h;
    h[0] = (_Float16)v.x; h[1] = (_Float16)v.y; h[2] = (_Float16)v.z; h[3] = (_Float16)v.w;
    *(half4*)(Xh + (size_t)row * DIM + 4 * lane) = h;
  }
}

// normalized init -> mu_f16 [cluster][dim] row-major
__global__ void prep0f_kernel(const float* __restrict__ init,
                              _Float16* __restrict__ muh) {
  int k = blockIdx.x, lane = threadIdx.x;  // 64 blocks x 64 lanes
  float4 v = *(const float4*)(init + (size_t)k * DIM + 4 * lane);
  float s = v.x * v.x;
  s = fmaf(v.y, v.y, s); s = fmaf(v.z, v.z, s); s = fmaf(v.w, v.w, s);
  s = wave_reduce_sum(s);
  float inv = 1.0f / fmaxf(sqrtf(s), EPSV);
  half4 h;
  h[0] = (_Float16)(v.x * inv); h[1] = (_Float16)(v.y * inv);
  h[2] = (_Float16)(v.z * inv); h[3] = (_Float16)(v.w * inv);
  *(half4*)(muh + (size_t)k * DIM + 4 * lane) = h;
}

// ---------------- staging helper ----------------
// 512B-row arrays (X tile rows, mu rows): 32 x 1KB chunks, swizzled source.
// LDS layout: elem(row,dim) at [row*DIM + (dim ^ ((row&7)<<3))]
__device__ __forceinline__ void stage_row512(const _Float16* g, _Float16* l,
                                             int wid, int lane) {
#pragma unroll
  for (int ii = 0; ii < 8; ++ii) {
    int i = wid * 8 + ii;
    int row = i * 2 + (lane >> 5);
    int slot = (lane & 31) ^ (row & 7);
    glds16((const char*)g + row * 512 + slot * 16, (char*)l + i * 1024);
  }
}

// ---------------- main kernel ----------------
template <int LAST>
__global__ __launch_bounds__(256, 1) void cluster_main(
    const _Float16* __restrict__ Xh, const _Float16* __restrict__ muh,
    const float* __restrict__ inv_norm, const float* __restrict__ beta,
    float* __restrict__ part_cm, float* __restrict__ part_cr,
    float* __restrict__ r_out) {
  __shared__ alignas(16) _Float16 mu_lds[KC * DIM];      // 32KB [cl][dim] swz
  __shared__ alignas(16) _Float16 x_lds[2][TR * DIM];    // 64KB [row][dim] swz
  __shared__ alignas(16) _Float16 xt_lds[DIM * TR];      // 32KB [dim][row] swz
  __shared__ alignas(16) _Float16 r_lds[KC * TR];        // 8KB  [cl][row] swz
  __shared__ float cr_lds[4 * KC];

  const int tid = threadIdx.x, wid = tid >> 6, lane = tid & 63;
  const int l15 = lane & 15, h = lane >> 4;
  const float b = beta[0];
  const int myrow = 16 * wid + l15;  // tile-local row this lane owns

  // prologue staging: mu + first X
  const int rb0 = blockIdx.x;
  stage_row512(muh, mu_lds, wid, lane);
  stage_row512(Xh + (size_t)rb0 * TR * DIM, x_lds[0], wid, lane);

  f32x4 acc2[4][4] = {};
  float cr_acc[16] = {};
  __syncthreads();  // full drain: mu + x[0] staged

  int p = 0;
  for (int rb = rb0; rb < NTILES; rb += NB, p ^= 1) {
    const int row0 = rb * TR;
    const int rbn = rb + NB;
    if (rbn < NTILES)  // prefetch next X tile into other buffer
      stage_row512(Xh + (size_t)rbn * TR * DIM, x_lds[p ^ 1], wid, lane);

    // ---- GEMM1: dist^T[cluster][xrow] = mu_norm @ X^T ----
    f32x4 acc1[4] = {};
    const _Float16* xb = x_lds[p];
#pragma unroll
    for (int t = 0; t < 8; ++t) {
      const int kb = 32 * t + 8 * h;
      half8 bx = *(const half8*)&xb[myrow * DIM + (kb ^ ((myrow & 7) << 3))];
#pragma unroll
      for (int m = 0; m < 4; ++m) {
        const int cl = 16 * m + l15;
        half8 am = *(const half8*)&mu_lds[cl * DIM + (kb ^ ((cl & 7) << 3))];
        acc1[m] = __builtin_amdgcn_mfma_f32_16x16x32_f16(am, bx, acc1[m], 0, 0, 0);
      }
    }

    // ---- in-LDS transpose: x[p] (64 rows x 256 dims) -> xt_lds [dim][row] ----
    // thread t: dim-block db = t>>3 (8 dims), row-block rb8 = t&7 (8 rows).
    // 8x8 f16 block transposed in registers via v_perm_b32.
    // xt hazard vs previous tile's GEMM2: protected by previous sync2.
    {
      const int db = tid >> 3;
      const int rb8 = tid & 7;
      union U { uint4 v; unsigned u[4]; };
      U tin[8];
#pragma unroll
      for (int k2 = 0; k2 < 8; ++k2)  // row = 8*rb8+k2 -> row&7 == k2
        tin[k2].v = *(const uint4*)&xb[(8 * rb8 + k2) * DIM + ((8 * db) ^ (k2 << 3))];
#pragma unroll
      for (int j = 0; j < 8; ++j) {
        const unsigned sel = (j & 1) ? 0x07060302u : 0x05040100u;
        U o;
#pragma unroll
        for (int m2 = 0; m2 < 4; ++m2)
          o.u[m2] = __builtin_amdgcn_perm(tin[2 * m2 + 1].u[j >> 1],
                                          tin[2 * m2].u[j >> 1], sel);
        // dm = 8*db+j, dm&7 == j; rowstart = 8*rb8; swz = rowstart ^ (j<<3)
        *(uint4*)&xt_lds[(8 * db + j) * TR + 8 * (rb8 ^ j)] = o.v;
      }
    }

    // ---- softmax over 64 clusters for this lane's row ----
    const int xr = row0 + myrow;
    const float sc = b * inv_norm[xr];
#pragma unroll
    for (int m = 0; m < 4; ++m)
#pragma unroll
      for (int j = 0; j < 4; ++j) acc1[m][j] *= sc;
    float mx = -1e30f;
#pragma unroll
    for (int m = 0; m < 4; ++m)
#pragma unroll
      for (int j = 0; j < 4; ++j) mx = fmaxf(mx, acc1[m][j]);
    mx = fmaxf(mx, __shfl_xor(mx, 16));
    mx = fmaxf(mx, __shfl_xor(mx, 32));
    float esum = 0.f;
#pragma unroll
    for (int m = 0; m < 4; ++m)
#pragma unroll
      for (int j = 0; j < 4; ++j) {
        float e = __expf(acc1[m][j] - mx);
        acc1[m][j] = e;
        esum += e;
      }
    esum += __shfl_xor(esum, 16);
    esum += __shfl_xor(esum, 32);
    const float rcp = 1.0f / esum;
#pragma unroll
    for (int m = 0; m < 4; ++m) {
#pragma unroll
      for (int j = 0; j < 4; ++j) {
        const float rv = acc1[m][j] * rcp;
        acc1[m][j] = rv;
        const int cl = 16 * m + 4 * h + j;
        cr_acc[m * 4 + j] += rv;
        r_lds[cl * TR + (myrow ^ ((cl & 7) << 3))] = (_Float16)rv;
      }
      if (LAST)  // coalesced 16B store: lane owns cl = 16m+4h..16m+4h+3 of row xr
        *(float4*)&r_out[(size_t)xr * KC + 16 * m + 4 * h] = *(float4*)&acc1[m];
    }

    // sync1: r_lds + xt_lds writes visible. LDS-only — X prefetch stays in flight.
    barrier_lgkm_only();

    // ---- GEMM2: cluster_mean[cluster][dim] += r^T @ X ----
#pragma unroll
    for (int t = 0; t < 2; ++t) {
      const int kb = 32 * t + 8 * h;
      half8 ar[4], bx2[4];
#pragma unroll
      for (int m = 0; m < 4; ++m) {
        const int cl = 16 * m + l15;
        ar[m] = *(const half8*)&r_lds[cl * TR + (kb ^ ((cl & 7) << 3))];
      }
#pragma unroll
      for (int n = 0; n < 4; ++n) {
        const int dm = 64 * wid + 16 * n + l15;
        bx2[n] = *(const half8*)&xt_lds[dm * TR + (kb ^ ((dm & 7) << 3))];
      }
#pragma unroll
      for (int m = 0; m < 4; ++m)
#pragma unroll
        for (int n = 0; n < 4; ++n)
          acc2[m][n] = __builtin_amdgcn_mfma_f32_16x16x32_f16(ar[m], bx2[n], acc2[m][n], 0, 0, 0);
    }
    // sync2: full drain — next tile's GEMM1/transpose need x[p^1] fully staged
    // (all waves), and xt/r free for overwrite.
    __syncthreads();
  }

  // epilogue: per-block partials
  float* pc = part_cm + (size_t)blockIdx.x * (KC * DIM);
#pragma unroll
  for (int m = 0; m < 4; ++m)
#pragma unroll
    for (int n = 0; n < 4; ++n)
#pragma unroll
      for (int j = 0; j < 4; ++j)
        pc[(16 * m + 4 * h + j) * DIM + 64 * wid + 16 * n + l15] = acc2[m][n][j];
#pragma unroll
  for (int m = 0; m < 4; ++m)
#pragma unroll
    for (int j = 0; j < 4; ++j) {
      float v = cr_acc[m * 4 + j];
      v += __shfl_xor(v, 1); v += __shfl_xor(v, 2);
      v += __shfl_xor(v, 4); v += __shfl_xor(v, 8);
      if (l15 == 0) cr_lds[wid * KC + 16 * m + 4 * h + j] = v;
    }
  __syncthreads();
  if (wid == 0)
    part_cr[(size_t)blockIdx.x * KC + lane] =
        cr_lds[lane] + cr_lds[KC + lane] + cr_lds[2 * KC + lane] + cr_lds[3 * KC + lane];
}

// ---------------- 2-stage parallel reduce ----------------
// stage 1: grid (KC, NG2), 256 thr; each block sums 32 of the NB partials for
// one cluster, all 256 dims. 512 blocks, 32 coalesced loads/thread.
__global__ void reduce_cm_kernel(const float* __restrict__ part_cm,
                                 float* __restrict__ part2) {
  const int k = blockIdx.x, g = blockIdx.y, t = threadIdx.x;
  float s = 0.f;
#pragma unroll
  for (int b = 0; b < NB / NG2; ++b)
    s += part_cm[(size_t)(g * (NB / NG2) + b) * (KC * DIM) + k * DIM + t];
  part2[(size_t)g * (KC * DIM) + k * DIM + t] = s;
}

// stage 2: grid KC, 256 thr. Sum NG2 group-partials + cr, divide, (re)normalize.
template <int FINAL>
__global__ void norm_kernel(const float* __restrict__ part2,
                            const float* __restrict__ part_cr,
                            _Float16* __restrict__ muh,
                            float* __restrict__ mu_out) {
  const int k = blockIdx.x, t = threadIdx.x;
  __shared__ float red[256];
  red[t] = part_cr[(size_t)t * KC + k];  // bl = t (NB == 256)
  __syncthreads();
#pragma unroll
  for (int off = 128; off > 0; off >>= 1) {
    if (t < off) red[t] += red[t + off];
    __syncthreads();
  }
  const float crv = red[0];
  __syncthreads();
  float s = 0.f;
#pragma unroll
  for (int g = 0; g < NG2; ++g) s += part2[(size_t)g * (KC * DIM) + k * DIM + t];
  const float mu = s / crv;
  if (FINAL) {
    mu_out[k * DIM + t] = mu;
    return;
  }
  red[t] = mu * mu;
  __syncthreads();
#pragma unroll
  for (int off = 128; off > 0; off >>= 1) {
    if (t < off) red[t] += red[t + off];
    __syncthreads();
  }
  const float inv = 1.0f / fmaxf(sqrtf(red[0]), EPSV);
  muh[k * DIM + t] = (_Float16)(mu * inv);
}

// ================= v1 fallback (round-1 fp32 path) =================
__global__ void rownorm_v1(const float* __restrict__ embeds, float* __restrict__ inv_norm) {
  int gw = (blockIdx.x * blockDim.x + threadIdx.x) >> 6;
  int lane = threadIdx.x & 63;
  int nw = (gridDim.x * blockDim.x) >> 6;
  for (int row = gw; row < N_ROWS; row += nw) {
    const float* rp = embeds + (size_t)row * DIM;
    float s = 0.f;
#pragma unroll
    for (int j = 0; j < 4; ++j) { float v = rp[lane + 64 * j]; s = fmaf(v, v, s); }
    s = wave_reduce_sum(s);
    if (lane == 0) inv_norm[row] = 1.0f / fmaxf(sqrtf(s), EPSV);
  }
}
__global__ void prep0_v1(const float* __restrict__ init, float* __restrict__ muT) {
  int k = blockIdx.x, lane = threadIdx.x;
  const float* rp = init + k * DIM;
  float v[4]; float s = 0.f;
#pragma unroll
  for (int j = 0; j < 4; ++j) { v[j] = rp[lane + 64 * j]; s = fmaf(v[j], v[j], s); }
  s = wave_reduce_sum(s);
  float inv = 1.0f / fmaxf(sqrtf(s), EPSV);
#pragma unroll
  for (int j = 0; j < 4; ++j) muT[(lane + 64 * j) * KC + k] = v[j] * inv;
}
__device__ __forceinline__ float wave_reduce_max_v1(float v) {
#pragma unroll
  for (int off = 32; off > 0; off >>= 1) v = fmaxf(v, __shfl_xor(v, off, 64));
  return v;
}
template <int LAST>
__global__ __launch_bounds__(256, 1) void main_v1(
    const float* __restrict__ embeds, const float* __restrict__ inv_norm,
    const float* __restrict__ muT, const float* __restrict__ beta,
    float* __restrict__ part_cm, float* __restrict__ part_cr,
    float* __restrict__ r_out, int nb) {
  __shared__ float mu_l[DIM * KC];
  __shared__ float x_l[TR * DIM];
  __shared__ float r_l[TR * KC];
  __shared__ float cr_l[4 * KC];
  const int tid = threadIdx.x, wid = tid >> 6, lane = tid & 63;
  const float b = beta[0];
  {
    const float4* m4 = (const float4*)muT; float4* ml4 = (float4*)mu_l;
#pragma unroll
    for (int i = 0; i < 16; ++i) ml4[tid + i * 256] = m4[tid + i * 256];
  }
  float acc[64];
#pragma unroll
  for (int i = 0; i < 64; ++i) acc[i] = 0.f;
  float cr = 0.f;
  for (int rb = blockIdx.x; rb < NTILES; rb += nb) {
    const int row0 = rb * TR;
    __syncthreads();
    {
      const float4* x4 = (const float4*)(embeds + (size_t)row0 * DIM);
      float4* xl4 = (float4*)x_l;
#pragma unroll
      for (int i = 0; i < 16; ++i) xl4[tid + i * 256] = x4[tid + i * 256];
    }
    __syncthreads();
    float dist[16];
#pragma unroll
    for (int r = 0; r < 16; ++r) dist[r] = 0.f;
    const int rbase = wid * 16;
    for (int d = 0; d < DIM; d += 4) {
      float mv0 = mu_l[(d + 0) * KC + lane], mv1 = mu_l[(d + 1) * KC + lane];
      float mv2 = mu_l[(d + 2) * KC + lane], mv3 = mu_l[(d + 3) * KC + lane];
#pragma unroll
      for (int r = 0; r < 16; ++r) {
        float4 xv = *(const float4*)&x_l[(rbase + r) * DIM + d];
        dist[r] = fmaf(xv.x, mv0, dist[r]); dist[r] = fmaf(xv.y, mv1, dist[r]);
        dist[r] = fmaf(xv.z, mv2, dist[r]); dist[r] = fmaf(xv.w, mv3, dist[r]);
      }
    }
#pragma unroll
    for (int r = 0; r < 16; ++r) {
      const int row = rbase + r;
      float s = b * (dist[r] * inv_norm[row0 + row]);
      float m = wave_reduce_max_v1(s);
      float e = __expf(s - m);
      float sum = wave_reduce_sum(e);
      float rv = e * (1.0f / sum);
      cr += rv;
      r_l[row * KC + lane] = rv;
      if (LAST) r_out[(size_t)(row0 + row) * KC + lane] = rv;
    }
    __syncthreads();
    const int dbase = wid * 64;
    for (int row = 0; row < TR; ++row) {
      float rv = r_l[row * KC + lane];
#pragma unroll
      for (int dd = 0; dd < 64; dd += 4) {
        float4 xv = *(const float4*)&x_l[row * DIM + dbase + dd];
        acc[dd + 0] = fmaf(rv, xv.x, acc[dd + 0]); acc[dd + 1] = fmaf(rv, xv.y, acc[dd + 1]);
        acc[dd + 2] = fmaf(rv, xv.z, acc[dd + 2]); acc[dd + 3] = fmaf(rv, xv.w, acc[dd + 3]);
      }
    }
  }
  {
    float* pp = part_cm + ((size_t)blockIdx.x * KC + lane) * DIM + wid * 64;
#pragma unroll
    for (int dd = 0; dd < 64; dd += 4)
      *(float4*)&pp[dd] = make_float4(acc[dd], acc[dd + 1], acc[dd + 2], acc[dd + 3]);
    cr_l[wid * KC + lane] = cr;
  }
  __syncthreads();
  if (wid == 0) {
    float c = cr_l[lane] + cr_l[64 + lane] + cr_l[128 + lane] + cr_l[192 + lane];
    part_cr[(size_t)blockIdx.x * KC + lane] = c;
  }
}
template <int FINAL>
__global__ void reduce_v1(const float* __restrict__ part_cm, const float* __restrict__ part_cr,
                          float* __restrict__ muT, float* __restrict__ mu_out, int nb) {
  const int k = blockIdx.x, t = threadIdx.x;
  __shared__ float red[256];
  float s = 0.f;
  for (int bl = 0; bl < nb; ++bl) s += part_cm[((size_t)bl * KC + k) * DIM + t];
  float c = 0.f;
  for (int bl = t; bl < nb; bl += 256) c += part_cr[(size_t)bl * KC + k];
  red[t] = c; __syncthreads();
#pragma unroll
  for (int off = 128; off > 0; off >>= 1) { if (t < off) red[t] += red[t + off]; __syncthreads(); }
  const float crv = red[0]; __syncthreads();
  const float mu = s / crv;
  if (FINAL) { mu_out[k * DIM + t] = mu; return; }
  red[t] = mu * mu; __syncthreads();
#pragma unroll
  for (int off = 128; off > 0; off >>= 1) { if (t < off) red[t] += red[t + off]; __syncthreads(); }
  const float inv = 1.0f / fmaxf(sqrtf(red[0]), EPSV);
  muT[t * KC + k] = mu * inv;
}

// ================= launch =================
extern "C" void kernel_launch(void* const* d_in, const int* in_sizes, int n_in,
                              void* d_out, int out_size, void* d_ws, size_t ws_size,
                              hipStream_t stream) {
  const float* embeds = (const float*)d_in[0];
  const float* init = (const float*)d_in[1];
  const float* beta = (const float*)d_in[2];
  float* out_mu = (float*)d_out;
  float* out_r = out_mu + KC * DIM;
  char* ws = (char*)d_ws;

  const size_t szX = (size_t)N_ROWS * DIM * 2;   // 102.4 MB
  const size_t szInv = (size_t)N_ROWS * 4;
  const size_t szMu = (size_t)KC * DIM * 2;
  const size_t szPC = (size_t)NB * KC * DIM * 4;
  const size_t szPR = (size_t)NB * KC * 4;
  const size_t szP2 = (size_t)NG2 * KC * DIM * 4;
  const size_t need = szX + szInv + szMu + szPC + szPR + szP2;

  if (ws_size >= need) {
    _Float16* Xh = (_Float16*)ws;
    float* invn = (float*)(ws + szX);
    _Float16* muh = (_Float16*)(ws + szX + szInv);
    float* pcm = (float*)(ws + szX + szInv + szMu);
    float* pcr = (float*)(ws + szX + szInv + szMu + szPC);
    float* p2 = (float*)(ws + szX + szInv + szMu + szPC + szPR);

    rn_convert_kernel<<<2048, 256, 0, stream>>>(embeds, invn, Xh);
    prep0f_kernel<<<KC, 64, 0, stream>>>(init, muh);
    for (int it = 0; it < NUM_ITER; ++it) {
      if (it > 0) {
        reduce_cm_kernel<<<dim3(KC, NG2), 256, 0, stream>>>(pcm, p2);
        norm_kernel<0><<<KC, 256, 0, stream>>>(p2, pcr, muh, nullptr);
      }
      if (it == NUM_ITER - 1)
        cluster_main<1><<<NB, 256, 0, stream>>>(Xh, muh, invn, beta, pcm, pcr, out_r);
      else
        cluster_main<0><<<NB, 256, 0, stream>>>(Xh, muh, invn, beta, pcm, pcr, out_r);
    }
    reduce_cm_kernel<<<dim3(KC, NG2), 256, 0, stream>>>(pcm, p2);
    norm_kernel<1><<<KC, 256, 0, stream>>>(p2, pcr, nullptr, out_mu);
  } else {
    // v1 fp32 fallback
    float* wsf = (float*)d_ws;
    float* muT = wsf;
    float* invn = muT + DIM * KC;
    size_t avail = ws_size / sizeof(float);
    size_t fixed = (size_t)DIM * KC + N_ROWS;
    size_t per_blk = (size_t)KC * DIM + KC;
    int nb = 256;
    if (avail > fixed) {
      size_t mx = (avail - fixed) / per_blk;
      if (mx < 256) nb = (int)mx;
    } else nb = 1;
    if (nb < 1) nb = 1;
    float* pcm = invn + N_ROWS;
    float* pcr = pcm + (size_t)nb * KC * DIM;

    rownorm_v1<<<2048, 256, 0, stream>>>(embeds, invn);
    prep0_v1<<<KC, 64, 0, stream>>>(init, muT);
    for (int it = 0; it < NUM_ITER; ++it) {
      if (it > 0) reduce_v1<0><<<KC, 256, 0, stream>>>(pcm, pcr, muT, nullptr, nb);
      if (it == NUM_ITER - 1)
        main_v1<1><<<nb, 256, 0, stream>>>(embeds, invn, muT, beta, pcm, pcr, out_r, nb);
      else
        main_v1<0><<<nb, 256, 0, stream>>>(embeds, invn, muT, beta, pcm, pcr, nullptr, nb);
    }
    reduce_v1<1><<<KC, 256, 0, stream>>>(pcm, pcr, muT, out_mu, nb);
  }
}